// Round 1
// baseline (276.866 us; speedup 1.0000x reference)
//
#include <hip/hip_runtime.h>

// Iterated 3x3 median blur, edge-replicate padding.
// out[b] = median_blur^{t[b]}(x[b]), t[b] in [0,10), fixed 10 scan steps.
// Ping-pong: step j (0-indexed) writes ws if j even, d_out if j odd.
// Step 9 (last) is odd -> lands in d_out.

#define SORT2(a,b) { float t_ = fminf(a,b); (b) = fmaxf(a,b); (a) = t_; }

__global__ __launch_bounds__(256) void median_step_kernel(
    const float* __restrict__ src, float* __restrict__ dst,
    const int* __restrict__ t, int j)
{
    const int W = 512, H = 512;
    int idx = blockIdx.x * blockDim.x + threadIdx.x;
    int b   = idx >> 18;          // 512*512 = 2^18 pixels per image
    int rem = idx & 262143;
    int y   = rem >> 9;
    int x   = rem & 511;
    const float* img = src + (b << 18);

    // Per-batch active flag; uniform across the block (blocks never straddle
    // a batch: 2^18 % 256 == 0), so this branch is wave-uniform.
    bool active = (j < t[b]);

    float out;
    if (active) {
        int ym = (y > 0)     ? y - 1 : 0;
        int yp = (y < H - 1) ? y + 1 : H - 1;
        int xm = (x > 0)     ? x - 1 : 0;
        int xp = (x < W - 1) ? x + 1 : W - 1;
        float p0 = img[ym * W + xm], p1 = img[ym * W + x], p2 = img[ym * W + xp];
        float p3 = img[y  * W + xm], p4 = img[y  * W + x], p5 = img[y  * W + xp];
        float p6 = img[yp * W + xm], p7 = img[yp * W + x], p8 = img[yp * W + xp];
        // Median-of-9, 19-exchange network (branchless min/max).
        SORT2(p1,p2); SORT2(p4,p5); SORT2(p7,p8);
        SORT2(p0,p1); SORT2(p3,p4); SORT2(p6,p7);
        SORT2(p1,p2); SORT2(p4,p5); SORT2(p7,p8);
        SORT2(p0,p3); SORT2(p5,p8); SORT2(p4,p7);
        SORT2(p3,p6); SORT2(p1,p4); SORT2(p2,p5);
        SORT2(p4,p7); SORT2(p4,p2); SORT2(p6,p4);
        SORT2(p4,p2);
        out = p4;
    } else {
        out = img[y * W + x];
    }
    dst[idx] = out;
}

extern "C" void kernel_launch(void* const* d_in, const int* in_sizes, int n_in,
                              void* d_out, int out_size, void* d_ws, size_t ws_size,
                              hipStream_t stream) {
    const float* x   = (const float*)d_in[0];
    const int*   t   = (const int*)d_in[1];
    float*       out = (float*)d_out;
    float*       ws  = (float*)d_ws;

    const int total = 32 * 512 * 512;
    dim3 block(256);
    dim3 grid(total / 256);

    const float* src = x;
    for (int j = 0; j < 10; ++j) {
        float* dst = ((j & 1) == 0) ? ws : out;   // j=9 (last) -> d_out
        median_step_kernel<<<grid, block, 0, stream>>>(src, dst, t, j);
        src = dst;
    }
}

// Round 2
// 148.334 us; speedup vs baseline: 1.8665x; 1.8665x over previous
//
#include <hip/hip_runtime.h>

// Fused iterated 3x3 median blur (edge-replicate), up to 10 iterations in LDS.
// Tile: 62x62 output + 10-halo = 82x82 LDS tile, single buffer + register
// staging (2 barriers/iter). Each iteration computes the fixed region
// [1,80]^2; the stale ring grows 1 cell/iter, leaving [10,71]^2 valid after
// 10 iters — exactly the output tile. Edge replication is maintained by
// computing each cell's median centered at its CLAMPED image coordinates.

#define TD 82        // tile dim with halo
#define TW 62        // output tile dim
#define RAD 10       // halo = max iterations
#define NT 256

__device__ __forceinline__ float min3f(float a, float b, float c) { return fminf(fminf(a, b), c); }
__device__ __forceinline__ float max3f(float a, float b, float c) { return fmaxf(fmaxf(a, b), c); }
__device__ __forceinline__ float med3f(float a, float b, float c) { return __builtin_amdgcn_fmed3f(a, b, c); }

__global__ __launch_bounds__(NT) void median_fused_kernel(
    const float* __restrict__ src, float* __restrict__ dst,
    const int* __restrict__ t)
{
    __shared__ float buf[TD * TD];

    const int b    = blockIdx.y;
    const int tile = blockIdx.x;           // 0..80 (9x9 tiles of 62)
    const int y0   = (tile / 9) * TW;
    const int x0   = (tile % 9) * TW;
    const int tid  = threadIdx.x;
    const float* img = src + (b << 18);

    // ---- load 82x82 halo tile, clamped to image ----
    for (int i = tid; i < TD * TD; i += NT) {
        int r = i / TD, c = i - r * TD;
        int gy = min(max(y0 - RAD + r, 0), 511);
        int gx = min(max(x0 - RAD + c, 0), 511);
        buf[i] = img[(gy << 9) + gx];
    }

    // cell-space clamp bounds: cell u maps to image row y0+u-RAD
    const int uLo = RAD - y0, uHi = 511 + RAD - y0;
    const int vLo = RAD - x0, vHi = 511 + RAD - x0;
    const bool interior = (uLo <= 1) && (uHi >= TD - 2) && (vLo <= 1) && (vHi >= TD - 2);

    int T = t[b];
    T = min(max(T, 0), 10);

    const int tx  = tid & 15;   // 16 column groups x 5 cols
    const int ty4 = tid >> 4;   // 16 row groups x 5 rows (stride 16)

    __syncthreads();

    for (int k = 0; k < T; ++k) {
        float stage[25];
        if (interior) {
            // fast path: sliding sorted-column-triple window, no clamping
            #pragma unroll
            for (int i = 0; i < 5; ++i) {
                int u = 1 + ty4 + (i << 4);
                const float* r0 = &buf[(u - 1) * TD + tx * 5];  // col (1+5tx)-1
                const float* r1 = r0 + TD;
                const float* r2 = r1 + TD;
                float lo[7], mi[7], hi[7];
                #pragma unroll
                for (int j = 0; j < 7; ++j) {
                    float a = r0[j], bb = r1[j], c = r2[j];
                    lo[j] = min3f(a, bb, c);
                    mi[j] = med3f(a, bb, c);
                    hi[j] = max3f(a, bb, c);
                }
                #pragma unroll
                for (int j = 0; j < 5; ++j)
                    stage[i * 5 + j] = med3f(max3f(lo[j], lo[j+1], lo[j+2]),
                                             med3f(mi[j], mi[j+1], mi[j+2]),
                                             min3f(hi[j], hi[j+1], hi[j+2]));
            }
        } else {
            // border path: median centered at clamped coords (maintains
            // replicate padding inside the halo)
            #pragma unroll
            for (int i = 0; i < 5; ++i) {
                int u  = 1 + ty4 + (i << 4);
                int cu = min(max(u, uLo), uHi);
                #pragma unroll
                for (int j = 0; j < 5; ++j) {
                    int v  = 1 + tx * 5 + j;
                    int cv = min(max(v, vLo), vHi);
                    const float* p = &buf[(cu - 1) * TD + (cv - 1)];
                    float a0 = p[0],      a1 = p[1],        a2 = p[2];
                    float b0 = p[TD],     b1 = p[TD + 1],   b2 = p[TD + 2];
                    float c0 = p[2*TD],   c1 = p[2*TD + 1], c2 = p[2*TD + 2];
                    float lo0 = min3f(a0,b0,c0), mi0 = med3f(a0,b0,c0), hi0 = max3f(a0,b0,c0);
                    float lo1 = min3f(a1,b1,c1), mi1 = med3f(a1,b1,c1), hi1 = max3f(a1,b1,c1);
                    float lo2 = min3f(a2,b2,c2), mi2 = med3f(a2,b2,c2), hi2 = max3f(a2,b2,c2);
                    stage[i * 5 + j] = med3f(max3f(lo0,lo1,lo2),
                                             med3f(mi0,mi1,mi2),
                                             min3f(hi0,hi1,hi2));
                }
            }
        }
        __syncthreads();   // all reads of old state done
        #pragma unroll
        for (int i = 0; i < 5; ++i) {
            int u = 1 + ty4 + (i << 4);
            #pragma unroll
            for (int j = 0; j < 5; ++j)
                buf[u * TD + (1 + tx * 5 + j)] = stage[i * 5 + j];
        }
        __syncthreads();   // all writes visible
    }

    // ---- store 62x62 output tile (coalesced) ----
    for (int i = tid; i < TW * TW; i += NT) {
        int r = i / TW, c = i - r * TW;
        int gy = y0 + r, gx = x0 + c;
        if (gy < 512 && gx < 512)
            dst[(b << 18) + (gy << 9) + gx] = buf[(r + RAD) * TD + (c + RAD)];
    }
}

extern "C" void kernel_launch(void* const* d_in, const int* in_sizes, int n_in,
                              void* d_out, int out_size, void* d_ws, size_t ws_size,
                              hipStream_t stream) {
    const float* x   = (const float*)d_in[0];
    const int*   t   = (const int*)d_in[1];
    float*       out = (float*)d_out;

    dim3 block(NT);
    dim3 grid(81, 32);   // 9x9 tiles x 32 batches
    median_fused_kernel<<<grid, block, 0, stream>>>(x, out, t);
}

// Round 3
// 117.621 us; speedup vs baseline: 2.3539x; 1.2611x over previous
//
#include <hip/hip_runtime.h>

// Fused iterated 3x3 median blur (edge-replicate), up to 10 iterations in LDS.
// 62x62 output tile + 10 halo = 82x82 LDS. Each thread owns a CONTIGUOUS 5x5
// patch (vertical register reuse: 49 LDS reads / 25 writes per iter).
// Replicate padding is maintained by a cheap per-iteration "pad refresh"
// (copy <=10-wide pad strips from clamped in-image edge cells) so EVERY cell
// uses the same unclamped fast path. Stale ring on tile-internal edges grows
// 1 cell/iter; after <=10 iters the output region [10,71]^2 is still valid.

#define TD 82
#define TW 62
#define RAD 10
#define NT 256

__device__ __forceinline__ float min3f(float a, float b, float c) { return fminf(fminf(a, b), c); }
__device__ __forceinline__ float max3f(float a, float b, float c) { return fmaxf(fmaxf(a, b), c); }
__device__ __forceinline__ float med3f(float a, float b, float c) { return __builtin_amdgcn_fmed3f(a, b, c); }

__global__ __launch_bounds__(NT) void median_fused_kernel(
    const float* __restrict__ src, float* __restrict__ dst,
    const int* __restrict__ t)
{
    __shared__ float buf[TD * TD];

    const int b    = blockIdx.y;
    const int tile = blockIdx.x;          // 9x9 tiles of 62
    const int y0   = (tile / 9) * TW;
    const int x0   = (tile % 9) * TW;
    const int tid  = threadIdx.x;
    const float* img = src + (b << 18);

    int T = t[b];
    T = min(max(T, 0), 10);

    if (T == 0) {                         // straight copy, no LDS
        for (int i = tid; i < TW * TW; i += NT) {
            int r = i / TW, c = i - r * TW;
            int gy = y0 + r, gx = x0 + c;
            if (gy < 512 && gx < 512)
                dst[(b << 18) + (gy << 9) + gx] = img[(gy << 9) + gx];
        }
        return;
    }

    // ---- load 82x82 halo tile, clamped (= replicate-padded image) ----
    for (int i = tid; i < TD * TD; i += NT) {
        int r = i / TD, c = i - r * TD;
        int gy = min(max(y0 - RAD + r, 0), 511);
        int gx = min(max(x0 - RAD + c, 0), 511);
        buf[i] = img[(gy << 9) + gx];
    }

    // image range in tile coords: tile (u,v) -> image (y0+u-RAD, x0+v-RAD)
    const int uLo = RAD - y0, uHi = 511 + RAD - y0;
    const int vLo = RAD - x0, vHi = 511 + RAD - x0;
    const int uLoC = max(uLo, 0), uHiC = min(uHi, TD - 1);
    const int vLoC = max(vLo, 0), vHiC = min(vHi, TD - 1);
    const int topN = max(uLo, 0);                                        // pad rows [0, uLo-1]
    const int botN = (uHi <= TD - 2) ? (min(TD - 1, uHi + RAD) - uHi) : 0; // pad rows [uHi+1, uHi+botN]
    const int lftN = max(vLo, 0);
    const int rgtN = (vHi <= TD - 2) ? (min(TD - 1, vHi + RAD) - vHi) : 0;
    const bool hasPad = (topN | botN | lftN | rgtN) != 0;                // block-uniform

    const int ptx = tid & 15;             // 16 col groups x 5
    const int pty = tid >> 4;             // 16 row groups x 5 (contiguous!)
    const int ub  = 1 + 5 * pty;
    const int vb  = 1 + 5 * ptx;
    float* wrow = &buf[ub * TD + vb];

    __syncthreads();

    for (int k = 0; k < T; ++k) {
        float A[7], Br[7], C[7], stage[25];
        const float* p = &buf[(ub - 1) * TD + (vb - 1)];
        #pragma unroll
        for (int j = 0; j < 7; ++j) A[j] = p[j];
        p += TD;
        #pragma unroll
        for (int j = 0; j < 7; ++j) Br[j] = p[j];
        #pragma unroll
        for (int i = 0; i < 5; ++i) {
            p += TD;
            #pragma unroll
            for (int j = 0; j < 7; ++j) C[j] = p[j];
            float lo[7], mi[7], hi[7];
            #pragma unroll
            for (int j = 0; j < 7; ++j) {
                lo[j] = min3f(A[j], Br[j], C[j]);
                mi[j] = med3f(A[j], Br[j], C[j]);
                hi[j] = max3f(A[j], Br[j], C[j]);
            }
            #pragma unroll
            for (int j = 0; j < 5; ++j)
                stage[i * 5 + j] = med3f(max3f(lo[j], lo[j+1], lo[j+2]),
                                         med3f(mi[j], mi[j+1], mi[j+2]),
                                         min3f(hi[j], hi[j+1], hi[j+2]));
            #pragma unroll
            for (int j = 0; j < 7; ++j) { A[j] = Br[j]; Br[j] = C[j]; }
        }
        __syncthreads();                  // reads of old state done
        #pragma unroll
        for (int i = 0; i < 5; ++i)
            #pragma unroll
            for (int j = 0; j < 5; ++j)
                wrow[i * TD + j] = stage[i * 5 + j];
        __syncthreads();                  // new state visible
        if (hasPad) {
            // refresh pad strips from clamped in-image cells (sources are
            // in-image -> never written here -> race-free; corner cells are
            // written twice with identical values)
            const int nh = (topN + botN) * TD;
            for (int i = tid; i < nh; i += NT) {
                int r = i / TD, c = i - r * TD;
                int u  = (r < topN) ? r : (uHi + 1 + r - topN);
                int cu = min(max(u, uLoC), uHiC);
                int cv = min(max(c, vLoC), vHiC);
                buf[u * TD + c] = buf[cu * TD + cv];
            }
            const int nv = (lftN + rgtN) * TD;
            for (int i = tid; i < nv; i += NT) {
                int ci = i / TD, r = i - ci * TD;
                int v  = (ci < lftN) ? ci : (vHi + 1 + ci - lftN);
                int cu = min(max(r, uLoC), uHiC);
                int cv = min(max(v, vLoC), vHiC);
                buf[r * TD + v] = buf[cu * TD + cv];
            }
            __syncthreads();
        }
    }

    // ---- store 62x62 output tile ----
    for (int i = tid; i < TW * TW; i += NT) {
        int r = i / TW, c = i - r * TW;
        int gy = y0 + r, gx = x0 + c;
        if (gy < 512 && gx < 512)
            dst[(b << 18) + (gy << 9) + gx] = buf[(r + RAD) * TD + (c + RAD)];
    }
}

extern "C" void kernel_launch(void* const* d_in, const int* in_sizes, int n_in,
                              void* d_out, int out_size, void* d_ws, size_t ws_size,
                              hipStream_t stream) {
    const float* x   = (const float*)d_in[0];
    const int*   t   = (const int*)d_in[1];
    float*       out = (float*)d_out;

    dim3 block(NT);
    dim3 grid(81, 32);
    median_fused_kernel<<<grid, block, 0, stream>>>(x, out, t);
}

// Round 4
// 110.953 us; speedup vs baseline: 2.4953x; 1.0601x over previous
//
#include <hip/hip_runtime.h>

// Fused iterated 3x3 median blur (edge-replicate), up to 9 iterations in LDS.
// KEY: t = randint(0,10) <= 9, so halo RAD=9 suffices -> 64x64 output tile
// + 2*9 halo = 82x82 LDS (26.9 KB), and 512/64 = 8x8 FULL tiles per batch
// (no partial tiles, no bounds checks, -21% blocks vs 62-tiles).
// Each thread owns a contiguous 5x5 patch of the [1,80]^2 compute region
// (6400 = 256*25 exactly). Valid region after k iters = [k,81-k]^2; after 9
// iters = [9,72]^2 = exactly the output tile. Replicate padding maintained
// by per-iteration pad refresh on image-edge tiles (block-uniform branch).

#define TD 82
#define OW 64
#define RAD 9
#define NT 256

__device__ __forceinline__ float min3f(float a, float b, float c) { return fminf(fminf(a, b), c); }
__device__ __forceinline__ float max3f(float a, float b, float c) { return fmaxf(fmaxf(a, b), c); }
__device__ __forceinline__ float med3f(float a, float b, float c) { return __builtin_amdgcn_fmed3f(a, b, c); }

__global__ __launch_bounds__(NT) void median_fused_kernel(
    const float* __restrict__ src, float* __restrict__ dst,
    const int* __restrict__ t)
{
    __shared__ float buf[TD * TD];

    const int b   = blockIdx.y;
    const int y0  = (blockIdx.x >> 3) * OW;   // 8x8 tiles of 64
    const int x0  = (blockIdx.x & 7) * OW;
    const int tid = threadIdx.x;
    const float* img  = src + (b << 18);
    float*       outb = dst + (b << 18);

    int T = t[b];
    T = min(max(T, 0), 9);

    const int sr = tid >> 4;            // store row group (16 rows x 4)
    const int sc = (tid & 15) << 2;     // store col (16 x float4)

    if (T == 0) {                       // straight vector copy, no LDS
        #pragma unroll
        for (int rr = 0; rr < 4; ++rr) {
            int gy = y0 + sr + rr * 16;
            *(float4*)&outb[(gy << 9) + x0 + sc] =
                *(const float4*)&img[(gy << 9) + x0 + sc];
        }
        return;
    }

    // ---- load 82x82 halo tile, clamped (= replicate-padded image) ----
    for (int i = tid; i < TD * TD; i += NT) {
        int r = i / TD, c = i - r * TD;
        int gy = min(max(y0 - RAD + r, 0), 511);
        int gx = min(max(x0 - RAD + c, 0), 511);
        buf[i] = img[(gy << 9) + gx];
    }

    // image range in tile coords: tile (u,v) -> image (y0+u-RAD, x0+v-RAD)
    const int uLo = RAD - y0, uHi = 511 + RAD - y0;
    const int vLo = RAD - x0, vHi = 511 + RAD - x0;
    const int uLoC = max(uLo, 0), uHiC = min(uHi, TD - 1);
    const int vLoC = max(vLo, 0), vHiC = min(vHi, TD - 1);
    const int topN = max(uLo, 0);
    const int botN = (uHi <= TD - 2) ? (min(TD - 1, uHi + RAD) - uHi) : 0;
    const int lftN = max(vLo, 0);
    const int rgtN = (vHi <= TD - 2) ? (min(TD - 1, vHi + RAD) - vHi) : 0;
    const bool hasPad = (topN | botN | lftN | rgtN) != 0;   // block-uniform

    const int ptx = tid & 15;           // 16 col groups x 5
    const int pty = tid >> 4;           // 16 row groups x 5 (contiguous)
    const int ub  = 1 + 5 * pty;
    const int vb  = 1 + 5 * ptx;
    float* wrow = &buf[ub * TD + vb];

    __syncthreads();

    for (int k = 0; k < T; ++k) {
        float A[7], Br[7], C[7], stage[25];
        const float* p = &buf[(ub - 1) * TD + (vb - 1)];
        #pragma unroll
        for (int j = 0; j < 7; ++j) A[j] = p[j];
        p += TD;
        #pragma unroll
        for (int j = 0; j < 7; ++j) Br[j] = p[j];
        #pragma unroll
        for (int i = 0; i < 5; ++i) {
            p += TD;
            #pragma unroll
            for (int j = 0; j < 7; ++j) C[j] = p[j];
            float lo[7], mi[7], hi[7];
            #pragma unroll
            for (int j = 0; j < 7; ++j) {
                lo[j] = min3f(A[j], Br[j], C[j]);
                mi[j] = med3f(A[j], Br[j], C[j]);
                hi[j] = max3f(A[j], Br[j], C[j]);
            }
            #pragma unroll
            for (int j = 0; j < 5; ++j)
                stage[i * 5 + j] = med3f(max3f(lo[j], lo[j+1], lo[j+2]),
                                         med3f(mi[j], mi[j+1], mi[j+2]),
                                         min3f(hi[j], hi[j+1], hi[j+2]));
            #pragma unroll
            for (int j = 0; j < 7; ++j) { A[j] = Br[j]; Br[j] = C[j]; }
        }
        __syncthreads();                // reads of old state done
        #pragma unroll
        for (int i = 0; i < 5; ++i)
            #pragma unroll
            for (int j = 0; j < 5; ++j)
                wrow[i * TD + j] = stage[i * 5 + j];
        __syncthreads();                // new state visible
        if (hasPad) {
            // refresh pad strips from clamped in-image cells (sources are
            // in-image -> never a destination -> race-free; corner pad cells
            // written twice with identical values)
            const int nh = (topN + botN) * TD;
            for (int i = tid; i < nh; i += NT) {
                int r = i / TD, c = i - r * TD;
                int u  = (r < topN) ? r : (uHi + 1 + r - topN);
                int cu = min(max(u, uLoC), uHiC);
                int cv = min(max(c, vLoC), vHiC);
                buf[u * TD + c] = buf[cu * TD + cv];
            }
            const int nv = (lftN + rgtN) * TD;
            for (int i = tid; i < nv; i += NT) {
                int ci = i / TD, r = i - ci * TD;
                int v  = (ci < lftN) ? ci : (vHi + 1 + ci - lftN);
                int cu = min(max(r, uLoC), uHiC);
                int cv = min(max(v, vLoC), vHiC);
                buf[r * TD + v] = buf[cu * TD + cv];
            }
            __syncthreads();
        }
    }

    // ---- store 64x64 output tile, float4, no bounds checks ----
    #pragma unroll
    for (int rr = 0; rr < 4; ++rr) {
        int row = sr + rr * 16;
        const float* s = &buf[(row + RAD) * TD + RAD + sc];
        float4 v = { s[0], s[1], s[2], s[3] };
        *(float4*)&outb[((y0 + row) << 9) + x0 + sc] = v;
    }
}

extern "C" void kernel_launch(void* const* d_in, const int* in_sizes, int n_in,
                              void* d_out, int out_size, void* d_ws, size_t ws_size,
                              hipStream_t stream) {
    const float* x   = (const float*)d_in[0];
    const int*   t   = (const int*)d_in[1];
    float*       out = (float*)d_out;

    dim3 block(NT);
    dim3 grid(64, 32);   // 8x8 full tiles x 32 batches
    median_fused_kernel<<<grid, block, 0, stream>>>(x, out, t);
}